// Round 5
// baseline (50.035 us; speedup 1.0000x reference)
//
#include <hip/hip_runtime.h>

// CrossNet: B=16384, D=1024, L=4, float32.
// x_{l+1} = x0*(x_l . w_l) + b_l + x_l
// Closed form: x_l = c_l*x0 + u_l,  u_l = sum_{j<l} b_j (row-independent),
//   c_{l+1} = c_l*(d_l+1) + s_l,  d_l = x0.w_l,  s_l = u_l.w_l,  c_0=1, u_0=0.
// out = c_4*x0 + u_4.
//
// K1 (1 wave): s1..s3 + u4 -> ws.   K2 (hot): pure stream, no LDS, no
// barrier, sequential-W dots, nontemporal X/Out, 2 rows per wave.

#define NB 16384
#define ROWS_PER_WAVE 2
#define NBLOCKS (NB / (4 * ROWS_PER_WAVE))  // 2048

// clang ext-vector type: valid for __builtin_nontemporal_{load,store}
typedef float f32x4 __attribute__((ext_vector_type(4)));

#define DOT4(a, b) ((a).x*(b).x + (a).y*(b).y + (a).z*(b).z + (a).w*(b).w)

// Full wave64 sum via DPP; lane 63 holds the total afterwards.
__device__ __forceinline__ float wave_sum64(float v) {
  float r = v;
  r += __int_as_float(__builtin_amdgcn_update_dpp(
      0, __float_as_int(r), 0x111, 0xf, 0xf, false));  // row_shr:1
  r += __int_as_float(__builtin_amdgcn_update_dpp(
      0, __float_as_int(r), 0x112, 0xf, 0xf, false));  // row_shr:2
  r += __int_as_float(__builtin_amdgcn_update_dpp(
      0, __float_as_int(r), 0x114, 0xf, 0xf, false));  // row_shr:4
  r += __int_as_float(__builtin_amdgcn_update_dpp(
      0, __float_as_int(r), 0x118, 0xf, 0xf, false));  // row_shr:8
  r += __int_as_float(__builtin_amdgcn_update_dpp(
      0, __float_as_int(r), 0x142, 0xa, 0xf, false));  // row_bcast:15
  r += __int_as_float(__builtin_amdgcn_update_dpp(
      0, __float_as_int(r), 0x143, 0xc, 0xf, false));  // row_bcast:31
  return r;
}

__device__ __forceinline__ float bcast63(float v) {
  return __int_as_float(__builtin_amdgcn_readlane(__float_as_int(v), 63));
}

// ---- K1: one wave computes s1..s3 and u4[1024] into ws ----
// ws layout (floats): ws[0..3] = {0, s1, s2, s3}; ws[4..1027] = u4.
__global__ __launch_bounds__(64) void crossnet_scalars(
    const float* __restrict__ W,     // [4,1024]
    const float* __restrict__ Bias,  // [4,1024]
    float* __restrict__ ws) {
  const int lane = threadIdx.x;  // 64 lanes, each owns 4 float4 (16 cols)
  const f32x4* W4 = (const f32x4*)W;
  const f32x4* B4 = (const f32x4*)Bias;

  float s1p = 0.f, s2p = 0.f, s3p = 0.f;
  f32x4 u[4];
#pragma unroll
  for (int k = 0; k < 4; ++k) {
    const int idx = lane + 64 * k;
    f32x4 b0 = B4[idx];
    f32x4 b1 = B4[256 + idx];
    f32x4 b2 = B4[512 + idx];
    f32x4 b3 = B4[768 + idx];
    f32x4 w1 = W4[256 + idx];
    f32x4 w2 = W4[512 + idx];
    f32x4 w3 = W4[768 + idx];
    f32x4 uu = b0;                                    // u1
    s1p += DOT4(uu, w1);
    uu += b1;                                         // u2
    s2p += DOT4(uu, w2);
    uu += b2;                                         // u3
    s3p += DOT4(uu, w3);
    uu += b3;                                         // u4
    u[k] = uu;
  }
  s1p = wave_sum64(s1p);
  s2p = wave_sum64(s2p);
  s3p = wave_sum64(s3p);
  if (lane == 63) {
    ws[0] = 0.0f;
    ws[1] = s1p;
    ws[2] = s2p;
    ws[3] = s3p;
  }
  f32x4* U4 = (f32x4*)(ws + 4);
#pragma unroll
  for (int k = 0; k < 4; ++k) U4[lane + 64 * k] = u[k];
}

// ---- K2: the hot stream. No LDS, no barrier. ----
__global__ __launch_bounds__(256, 5) void crossnet_main(
    const float* __restrict__ X,    // [16384,1024]
    const float* __restrict__ W,    // [4,1024]
    const float* __restrict__ ws,   // {0,s1,s2,s3} + u4[1024]
    float* __restrict__ Out) {      // [16384,1024]
  const int wave = threadIdx.x >> 6;
  const int lane = threadIdx.x & 63;
  const int row0 = (blockIdx.x * 4 + wave) * ROWS_PER_WAVE;

  const f32x4* Xa = (const f32x4*)X + (size_t)row0 * 256;
  const f32x4* Xb = Xa + 256;
  f32x4* Oa = (f32x4*)Out + (size_t)row0 * 256;
  f32x4* Ob = Oa + 256;
  const f32x4* W4 = (const f32x4*)W;

  // X rows: nontemporal (no reuse), issued first (HBM latency)
  f32x4 xa[4], xb[4];
#pragma unroll
  for (int k = 0; k < 4; ++k) xa[k] = __builtin_nontemporal_load(&Xa[lane + 64 * k]);
#pragma unroll
  for (int k = 0; k < 4; ++k) xb[k] = __builtin_nontemporal_load(&Xb[lane + 64 * k]);

  // dots: consume W one l-block at a time (keeps VGPR low; compiler pipelines)
  float pa0 = 0.f, pa1 = 0.f, pa2 = 0.f, pa3 = 0.f;
  float pb0 = 0.f, pb1 = 0.f, pb2 = 0.f, pb3 = 0.f;
#pragma unroll
  for (int l = 0; l < 4; ++l) {
    f32x4 w0 = W4[l * 256 + lane];
    f32x4 w1 = W4[l * 256 + lane + 64];
    f32x4 w2 = W4[l * 256 + lane + 128];
    f32x4 w3 = W4[l * 256 + lane + 192];
    float da = DOT4(xa[0], w0) + DOT4(xa[1], w1) + DOT4(xa[2], w2) + DOT4(xa[3], w3);
    float db = DOT4(xb[0], w0) + DOT4(xb[1], w1) + DOT4(xb[2], w2) + DOT4(xb[3], w3);
    if (l == 0) { pa0 = da; pb0 = db; }
    else if (l == 1) { pa1 = da; pb1 = db; }
    else if (l == 2) { pa2 = da; pb2 = db; }
    else { pa3 = da; pb3 = db; }
  }

  // u4 for this lane's 16 columns: issue before the reduce (hide L2 latency)
  const f32x4* U4 = (const f32x4*)(ws + 4);
  f32x4 u4r[4];
#pragma unroll
  for (int k = 0; k < 4; ++k) u4r[k] = U4[lane + 64 * k];
  const f32x4 sv = *(const f32x4*)ws;  // {0, s1, s2, s3} broadcast

  // 8 independent DPP reduce chains
  pa0 = wave_sum64(pa0); pa1 = wave_sum64(pa1);
  pa2 = wave_sum64(pa2); pa3 = wave_sum64(pa3);
  pb0 = wave_sum64(pb0); pb1 = wave_sum64(pb1);
  pb2 = wave_sum64(pb2); pb3 = wave_sum64(pb3);

  float ca = bcast63(pa0) + 1.0f;
  ca = ca * (bcast63(pa1) + 1.0f) + sv.y;
  ca = ca * (bcast63(pa2) + 1.0f) + sv.z;
  ca = ca * (bcast63(pa3) + 1.0f) + sv.w;
  float cb = bcast63(pb0) + 1.0f;
  cb = cb * (bcast63(pb1) + 1.0f) + sv.y;
  cb = cb * (bcast63(pb2) + 1.0f) + sv.z;
  cb = cb * (bcast63(pb3) + 1.0f) + sv.w;

  // epilogue: nontemporal streaming stores
#pragma unroll
  for (int k = 0; k < 4; ++k) {
    f32x4 o = ca * xa[k] + u4r[k];
    __builtin_nontemporal_store(o, &Oa[lane + 64 * k]);
  }
#pragma unroll
  for (int k = 0; k < 4; ++k) {
    f32x4 o = cb * xb[k] + u4r[k];
    __builtin_nontemporal_store(o, &Ob[lane + 64 * k]);
  }
}

extern "C" void kernel_launch(void* const* d_in, const int* in_sizes, int n_in,
                              void* d_out, int out_size, void* d_ws, size_t ws_size,
                              hipStream_t stream) {
  const float* X = (const float*)d_in[0];     // inputs  [16384,1024]
  const float* W = (const float*)d_in[1];     // weights [4,1024]
  const float* Bias = (const float*)d_in[2];  // biases  [4,1024]
  float* Out = (float*)d_out;
  float* ws = (float*)d_ws;

  crossnet_scalars<<<1, 64, 0, stream>>>(W, Bias, ws);
  crossnet_main<<<NBLOCKS, 256, 0, stream>>>(X, W, ws, Out);
}

// Round 6
// 44.607 us; speedup vs baseline: 1.1217x; 1.1217x over previous
//
#include <hip/hip_runtime.h>

// CrossNet: B=16384, D=1024, L=4, float32.
// x_{l+1} = x0*(x_l . w_l) + b_l + x_l
// Closed form: x_l = c_l*x0 + u_l,  u_l = sum_{j<l} b_j (row-independent),
//   c_{l+1} = c_l*(d_l+1) + s_l,  d_l = x0.w_l,  s_l = u_l.w_l,  c_0=1, u_0=0.
// out = c_4*x0 + u_4.
//
// K1 (1 wave): s1..s3 + u4 -> ws.   K2 (hot): pure stream, no LDS, no
// barrier, sequential-W dots, 2 rows per wave. Plain cached loads/stores:
// R5 proved nontemporal stores cause 1.79x write amplification on gfx950
// (WRITE_SIZE 114.7MB vs 64MB) — X+Out (128MB) fits in the 256MB L3, so
// normal caching is strictly better here.

#define NB 16384
#define ROWS_PER_WAVE 2
#define NBLOCKS (NB / (4 * ROWS_PER_WAVE))  // 2048

typedef float f32x4 __attribute__((ext_vector_type(4)));

#define DOT4(a, b) ((a).x*(b).x + (a).y*(b).y + (a).z*(b).z + (a).w*(b).w)

// Full wave64 sum via DPP; lane 63 holds the total afterwards.
__device__ __forceinline__ float wave_sum64(float v) {
  float r = v;
  r += __int_as_float(__builtin_amdgcn_update_dpp(
      0, __float_as_int(r), 0x111, 0xf, 0xf, false));  // row_shr:1
  r += __int_as_float(__builtin_amdgcn_update_dpp(
      0, __float_as_int(r), 0x112, 0xf, 0xf, false));  // row_shr:2
  r += __int_as_float(__builtin_amdgcn_update_dpp(
      0, __float_as_int(r), 0x114, 0xf, 0xf, false));  // row_shr:4
  r += __int_as_float(__builtin_amdgcn_update_dpp(
      0, __float_as_int(r), 0x118, 0xf, 0xf, false));  // row_shr:8
  r += __int_as_float(__builtin_amdgcn_update_dpp(
      0, __float_as_int(r), 0x142, 0xa, 0xf, false));  // row_bcast:15
  r += __int_as_float(__builtin_amdgcn_update_dpp(
      0, __float_as_int(r), 0x143, 0xc, 0xf, false));  // row_bcast:31
  return r;
}

__device__ __forceinline__ float bcast63(float v) {
  return __int_as_float(__builtin_amdgcn_readlane(__float_as_int(v), 63));
}

// ---- K1: one wave computes s1..s3 and u4[1024] into ws ----
// ws layout (floats): ws[0..3] = {0, s1, s2, s3}; ws[4..1027] = u4.
__global__ __launch_bounds__(64) void crossnet_scalars(
    const float* __restrict__ W,     // [4,1024]
    const float* __restrict__ Bias,  // [4,1024]
    float* __restrict__ ws) {
  const int lane = threadIdx.x;  // 64 lanes, each owns 4 float4 (16 cols)
  const f32x4* W4 = (const f32x4*)W;
  const f32x4* B4 = (const f32x4*)Bias;

  float s1p = 0.f, s2p = 0.f, s3p = 0.f;
  f32x4 u[4];
#pragma unroll
  for (int k = 0; k < 4; ++k) {
    const int idx = lane + 64 * k;
    f32x4 b0 = B4[idx];
    f32x4 b1 = B4[256 + idx];
    f32x4 b2 = B4[512 + idx];
    f32x4 b3 = B4[768 + idx];
    f32x4 w1 = W4[256 + idx];
    f32x4 w2 = W4[512 + idx];
    f32x4 w3 = W4[768 + idx];
    f32x4 uu = b0;                                    // u1
    s1p += DOT4(uu, w1);
    uu += b1;                                         // u2
    s2p += DOT4(uu, w2);
    uu += b2;                                         // u3
    s3p += DOT4(uu, w3);
    uu += b3;                                         // u4
    u[k] = uu;
  }
  s1p = wave_sum64(s1p);
  s2p = wave_sum64(s2p);
  s3p = wave_sum64(s3p);
  if (lane == 63) {
    ws[0] = 0.0f;
    ws[1] = s1p;
    ws[2] = s2p;
    ws[3] = s3p;
  }
  f32x4* U4 = (f32x4*)(ws + 4);
#pragma unroll
  for (int k = 0; k < 4; ++k) U4[lane + 64 * k] = u[k];
}

// ---- K2: the hot stream. No LDS, no barrier, cached loads/stores. ----
__global__ __launch_bounds__(256, 5) void crossnet_main(
    const float* __restrict__ X,    // [16384,1024]
    const float* __restrict__ W,    // [4,1024]
    const float* __restrict__ ws,   // {0,s1,s2,s3} + u4[1024]
    float* __restrict__ Out) {      // [16384,1024]
  const int wave = threadIdx.x >> 6;
  const int lane = threadIdx.x & 63;
  const int row0 = (blockIdx.x * 4 + wave) * ROWS_PER_WAVE;

  const f32x4* Xa = (const f32x4*)X + (size_t)row0 * 256;
  const f32x4* Xb = Xa + 256;
  f32x4* Oa = (f32x4*)Out + (size_t)row0 * 256;
  f32x4* Ob = Oa + 256;
  const f32x4* W4 = (const f32x4*)W;

  // X rows: issued first (HBM latency)
  f32x4 xa[4], xb[4];
#pragma unroll
  for (int k = 0; k < 4; ++k) xa[k] = Xa[lane + 64 * k];
#pragma unroll
  for (int k = 0; k < 4; ++k) xb[k] = Xb[lane + 64 * k];

  // dots: consume W one l-block at a time (keeps VGPR low; compiler pipelines)
  float pa0 = 0.f, pa1 = 0.f, pa2 = 0.f, pa3 = 0.f;
  float pb0 = 0.f, pb1 = 0.f, pb2 = 0.f, pb3 = 0.f;
#pragma unroll
  for (int l = 0; l < 4; ++l) {
    f32x4 w0 = W4[l * 256 + lane];
    f32x4 w1 = W4[l * 256 + lane + 64];
    f32x4 w2 = W4[l * 256 + lane + 128];
    f32x4 w3 = W4[l * 256 + lane + 192];
    float da = DOT4(xa[0], w0) + DOT4(xa[1], w1) + DOT4(xa[2], w2) + DOT4(xa[3], w3);
    float db = DOT4(xb[0], w0) + DOT4(xb[1], w1) + DOT4(xb[2], w2) + DOT4(xb[3], w3);
    if (l == 0) { pa0 = da; pb0 = db; }
    else if (l == 1) { pa1 = da; pb1 = db; }
    else if (l == 2) { pa2 = da; pb2 = db; }
    else { pa3 = da; pb3 = db; }
  }

  // u4 for this lane's 16 columns: issue before the reduce (hide L2 latency)
  const f32x4* U4 = (const f32x4*)(ws + 4);
  f32x4 u4r[4];
#pragma unroll
  for (int k = 0; k < 4; ++k) u4r[k] = U4[lane + 64 * k];
  const f32x4 sv = *(const f32x4*)ws;  // {0, s1, s2, s3} broadcast

  // 8 independent DPP reduce chains
  pa0 = wave_sum64(pa0); pa1 = wave_sum64(pa1);
  pa2 = wave_sum64(pa2); pa3 = wave_sum64(pa3);
  pb0 = wave_sum64(pb0); pb1 = wave_sum64(pb1);
  pb2 = wave_sum64(pb2); pb3 = wave_sum64(pb3);

  float ca = bcast63(pa0) + 1.0f;
  ca = ca * (bcast63(pa1) + 1.0f) + sv.y;
  ca = ca * (bcast63(pa2) + 1.0f) + sv.z;
  ca = ca * (bcast63(pa3) + 1.0f) + sv.w;
  float cb = bcast63(pb0) + 1.0f;
  cb = cb * (bcast63(pb1) + 1.0f) + sv.y;
  cb = cb * (bcast63(pb2) + 1.0f) + sv.z;
  cb = cb * (bcast63(pb3) + 1.0f) + sv.w;

  // epilogue: cached stores (L3 absorbs the stream; 128MB working set fits)
#pragma unroll
  for (int k = 0; k < 4; ++k) {
    f32x4 o = ca * xa[k] + u4r[k];
    Oa[lane + 64 * k] = o;
  }
#pragma unroll
  for (int k = 0; k < 4; ++k) {
    f32x4 o = cb * xb[k] + u4r[k];
    Ob[lane + 64 * k] = o;
  }
}

extern "C" void kernel_launch(void* const* d_in, const int* in_sizes, int n_in,
                              void* d_out, int out_size, void* d_ws, size_t ws_size,
                              hipStream_t stream) {
  const float* X = (const float*)d_in[0];     // inputs  [16384,1024]
  const float* W = (const float*)d_in[1];     // weights [4,1024]
  const float* Bias = (const float*)d_in[2];  // biases  [4,1024]
  float* Out = (float*)d_out;
  float* ws = (float*)d_ws;

  crossnet_scalars<<<1, 64, 0, stream>>>(W, Bias, ws);
  crossnet_main<<<NBLOCKS, 256, 0, stream>>>(X, W, ws, Out);
}

// Round 7
// 27.044 us; speedup vs baseline: 1.8501x; 1.6494x over previous
//
#include <hip/hip_runtime.h>

// CrossNet: B=16384, D=1024, L=4, float32.
// x_{l+1} = x0*(x_l . w_l) + b_l + x_l
// Closed form: x_l = c_l*x0 + u_l,  u_l = sum_{j<l} b_j (row-independent),
//   c_{l+1} = c_l*(d_l+1) + s_l,  d_l = x0.w_l,  s_l = u_l.w_l,  c_0=1, u_0=0.
// out = c_4*x0 + u_4  -> single pass over X.
//
// R3 fused structure (best measured: 26.9us) + slimmed preamble:
//  - single kernel, barrier-late, DPP wave reduction
//  - preamble s-dots reuse the w[l][k] register fragments (k==wave), no
//    extra W loads (wave-uniform if-chain select, no runtime reg indexing)
//  - X loads issued first (HBM critical path); W/Bias are L2-hot
// R5/R6 lessons: no nontemporal (WRITE_SIZE 112MiB is store-stream
// intrinsic, not nt-caused); no 2-kernel split (hot kernel regressed 2x);
// u4 from LDS, not global.

#define NB 16384
#define NWAVES 4
#define NBLOCKS (NB / NWAVES)  // 4096, one row per wave

typedef float f32x4 __attribute__((ext_vector_type(4)));

#define DOT4(a, b) ((a).x*(b).x + (a).y*(b).y + (a).z*(b).z + (a).w*(b).w)

// Full wave64 sum via DPP; lane 63 holds the total afterwards.
__device__ __forceinline__ float wave_sum64(float v) {
  float r = v;
  r += __int_as_float(__builtin_amdgcn_update_dpp(
      0, __float_as_int(r), 0x111, 0xf, 0xf, false));  // row_shr:1
  r += __int_as_float(__builtin_amdgcn_update_dpp(
      0, __float_as_int(r), 0x112, 0xf, 0xf, false));  // row_shr:2
  r += __int_as_float(__builtin_amdgcn_update_dpp(
      0, __float_as_int(r), 0x114, 0xf, 0xf, false));  // row_shr:4
  r += __int_as_float(__builtin_amdgcn_update_dpp(
      0, __float_as_int(r), 0x118, 0xf, 0xf, false));  // row_shr:8
  r += __int_as_float(__builtin_amdgcn_update_dpp(
      0, __float_as_int(r), 0x142, 0xa, 0xf, false));  // row_bcast:15
  r += __int_as_float(__builtin_amdgcn_update_dpp(
      0, __float_as_int(r), 0x143, 0xc, 0xf, false));  // row_bcast:31
  return r;
}

__device__ __forceinline__ float bcast63(float v) {
  return __int_as_float(__builtin_amdgcn_readlane(__float_as_int(v), 63));
}

__global__ __launch_bounds__(256, 4) void crossnet_fused(
    const float* __restrict__ X,     // [16384, 1024]
    const float* __restrict__ W,     // [4, 1024]
    const float* __restrict__ Bias,  // [4, 1024]
    float* __restrict__ Out) {       // [16384, 1024]
  __shared__ f32x4 lds_u4[256];
  __shared__ float lds_s[NWAVES][3];

  const int t = threadIdx.x;
  const int wave = t >> 6;
  const int lane = t & 63;
  const int row = blockIdx.x * NWAVES + wave;

  const f32x4* W4 = (const f32x4*)W;
  const f32x4* B4 = (const f32x4*)Bias;
  const f32x4* Xr = (const f32x4*)X + (size_t)row * 256;
  f32x4* Or = (f32x4*)Out + (size_t)row * 256;

  // ---- issue loads: X first (HBM), then W, then Bias (L2-hot) ----
  f32x4 x[4];
#pragma unroll
  for (int k = 0; k < 4; ++k) x[k] = Xr[lane + 64 * k];

  f32x4 w[4][4];
#pragma unroll
  for (int l = 0; l < 4; ++l)
#pragma unroll
    for (int k = 0; k < 4; ++k)
      w[l][k] = W4[l * 256 + lane + 64 * k];

  f32x4 b0 = B4[t];
  f32x4 b1 = B4[256 + t];
  f32x4 b2 = B4[512 + t];
  f32x4 b3 = B4[768 + t];

  // ---- preamble: u4 + s-partials, reusing w[l][wave] (wave-uniform sel) ----
  // thread t=64*wave+lane owns columns [4t..4t+3]; its W fragment for those
  // columns is w[l][k] with k==wave (index lane+64*wave == t).
  f32x4 w1s, w2s, w3s;
  if (wave == 0)      { w1s = w[1][0]; w2s = w[2][0]; w3s = w[3][0]; }
  else if (wave == 1) { w1s = w[1][1]; w2s = w[2][1]; w3s = w[3][1]; }
  else if (wave == 2) { w1s = w[1][2]; w2s = w[2][2]; w3s = w[3][2]; }
  else                { w1s = w[1][3]; w2s = w[2][3]; w3s = w[3][3]; }

  f32x4 u = b0;                       // u1
  float s1p = DOT4(u, w1s);
  u += b1;                            // u2
  float s2p = DOT4(u, w2s);
  u += b2;                            // u3
  float s3p = DOT4(u, w3s);
  u += b3;                            // u4
  lds_u4[t] = u;

  s1p = wave_sum64(s1p);
  s2p = wave_sum64(s2p);
  s3p = wave_sum64(s3p);
  if (lane == 63) {
    lds_s[wave][0] = s1p;
    lds_s[wave][1] = s2p;
    lds_s[wave][2] = s3p;
  }

  // ---- row dots (x, w in regs) ----
  float p0 = 0.f, p1 = 0.f, p2 = 0.f, p3 = 0.f;
#pragma unroll
  for (int k = 0; k < 4; ++k) {
    p0 += DOT4(x[k], w[0][k]);
    p1 += DOT4(x[k], w[1][k]);
    p2 += DOT4(x[k], w[2][k]);
    p3 += DOT4(x[k], w[3][k]);
  }
  const float P0 = bcast63(wave_sum64(p0));
  const float P1 = bcast63(wave_sum64(p1));
  const float P2 = bcast63(wave_sum64(p2));
  const float P3 = bcast63(wave_sum64(p3));

  // ---- single barrier: s/u4 visible ----
  __syncthreads();

  const float s1 = lds_s[0][0] + lds_s[1][0] + lds_s[2][0] + lds_s[3][0];
  const float s2 = lds_s[0][1] + lds_s[1][1] + lds_s[2][1] + lds_s[3][1];
  const float s3 = lds_s[0][2] + lds_s[1][2] + lds_s[2][2] + lds_s[3][2];

  float c = P0 + 1.0f;                // c1 (s0 = 0)
  c = c * (P1 + 1.0f) + s1;
  c = c * (P2 + 1.0f) + s2;
  c = c * (P3 + 1.0f) + s3;

  // ---- epilogue: out = c*x + u4 ----
#pragma unroll
  for (int k = 0; k < 4; ++k) {
    f32x4 u4r = lds_u4[lane + 64 * k];
    Or[lane + 64 * k] = c * x[k] + u4r;
  }
}

extern "C" void kernel_launch(void* const* d_in, const int* in_sizes, int n_in,
                              void* d_out, int out_size, void* d_ws, size_t ws_size,
                              hipStream_t stream) {
  const float* X = (const float*)d_in[0];     // inputs  [16384,1024]
  const float* W = (const float*)d_in[1];     // weights [4,1024]
  const float* Bias = (const float*)d_in[2];  // biases  [4,1024]
  float* Out = (float*)d_out;

  crossnet_fused<<<NBLOCKS, 256, 0, stream>>>(X, W, Bias, Out);
}